// Round 4
// baseline (583.629 us; speedup 1.0000x reference)
//
#include <hip/hip_runtime.h>
#include <cmath>

#define LBINS 401
#define LL (LBINS * LBINS)          // 160801
#define MIN_SEP 2
#define ROWG 10                     // row groups per batch
#define RPB 41                      // rows per block (10*41 >= 401)

// accum float indices
#define ACC_HANY  401   // sum relu(c)*any_i*any_j
#define ACC_HCONV 402   // sum relu(c)*fwd_i*rev_j
#define ACC_SM    403   // sum c * maskf (|i-j|>=2)
#define ACC_SW    404   // sum c * same * maskf
#define ACC_FLOATS 405

// ---------------------------------------------------------------------------
__global__ void zero_kernel(float* __restrict__ wsf) {
    int t = threadIdx.x;
    if (t < ACC_FLOATS) wsf[t] = 0.0f;
}

// ---------------------------------------------------------------------------
// prep: per-(b,l) flag byte for final_kernel's closed-form counts.
// ---------------------------------------------------------------------------
__global__ void prep_kernel(const float* __restrict__ logits,
                            const int* __restrict__ ctcf,
                            unsigned char* __restrict__ flags,
                            int BL) {
    int t = blockIdx.x * blockDim.x + threadIdx.x;
    if (t < BL) {
        int o = ctcf[t];
        unsigned char f = 0;
        if (o == 1)  f |= 1;
        if (o == -1) f |= 2;
        if (o != 0)  f |= 4;
        if (logits[2 * t + 1] > logits[2 * t]) f |= 8;
        flags[t] = f;
    }
}

// ---------------------------------------------------------------------------
// main: block = (batch b, 41-row slice). Thread u owns fixed columns
// {u, u+128, u+256, u+384}; column masks live in registers, row flags in
// LDS. Inner loop: 4 coalesced cm dword loads + pure VALU + 4 LDS atomics.
// ---------------------------------------------------------------------------
__global__ __launch_bounds__(128)
void main_kernel(const float* __restrict__ cm,
                 const float* __restrict__ logits,
                 const int* __restrict__ ctcf,
                 float* __restrict__ accum,
                 int B) {
    int b  = blockIdx.x;
    int rg = blockIdx.y;
    int i0 = rg * RPB;
    int nrows = min(RPB, LBINS - i0);
    int u = threadIdx.x;

    __shared__ float lb[LBINS];
    __shared__ float4 rowf[RPB];
    __shared__ float red[2][4];

    for (int s = u; s < LBINS; s += 128) lb[s] = 0.f;

    if (u < nrows) {
        int idx = b * LBINS + i0 + u;
        int o = ctcf[idx];
        float anyf = (o != 0) ? 1.f : 0.f;
        float fwdf = (o == 1) ? 1.f : 0.f;
        float cmpf = (logits[2 * idx + 1] > logits[2 * idx]) ? 1.f : 0.f;
        rowf[u] = make_float4(anyf, fwdf, cmpf, 0.f);
    }

    // column masks -> registers (once per block)
    bool ok3 = (u + 384) < LBINS;
    int   jj[4];
    float anyj[4], revj[4], cmpj[4];
    #pragma unroll
    for (int m = 0; m < 4; ++m) {
        int j = u + 128 * m;
        bool ok = (m < 3) || ok3;
        jj[m] = ok ? j : 0;
        int idx = b * LBINS + jj[m];
        int o = ctcf[idx];
        float l0 = logits[2 * idx], l1 = logits[2 * idx + 1];
        anyj[m] = (ok && o != 0)  ? 1.f : 0.f;
        revj[m] = (ok && o == -1) ? 1.f : 0.f;
        cmpj[m] = (ok && l1 > l0) ? 1.f : 0.f;
    }
    __syncthreads();

    const float* rowp = cm + (size_t)b * LL + (size_t)i0 * LBINS;
    float HA = 0.f, HC = 0.f, SW = 0.f, SM = 0.f;

    // 1-deep software pipeline over rows
    float c[4], nx[4];
    #pragma unroll
    for (int m = 0; m < 4; ++m) c[m] = rowp[jj[m]];
    if (!ok3) c[3] = 0.f;

    for (int r = 0; r < nrows; ++r) {
        const float* nextp = rowp + LBINS;
        if (r + 1 < nrows) {
            #pragma unroll
            for (int m = 0; m < 4; ++m) nx[m] = nextp[jj[m]];
        }
        int i = i0 + r;
        float4 rf = rowf[r];
        float an = 0.f, rv = 0.f, p1 = 0.f, smr = 0.f;
        #pragma unroll
        for (int m = 0; m < 4; ++m) {
            float cv = c[m];
            int d = i - jj[m]; d = d < 0 ? -d : d;
            float rc = fmaxf(cv, 0.f);
            an = fmaf(rc, anyj[m], an);
            rv = fmaf(rc, revj[m], rv);
            float cd = (d >= MIN_SEP) ? cv : 0.f;
            p1 = fmaf(cd, cmpj[m], p1);
            smr += cd;
            atomicAdd(&lb[d], cv);
        }
        HA = fmaf(rf.x, an, HA);
        HC = fmaf(rf.y, rv, HC);
        SW += (rf.z != 0.f) ? p1 : (smr - p1);
        SM += smr;
        #pragma unroll
        for (int m = 0; m < 4; ++m) c[m] = nx[m];
        if (!ok3) c[3] = 0.f;
        rowp = nextp;
    }

    #pragma unroll
    for (int off = 32; off > 0; off >>= 1) {
        HA += __shfl_down(HA, off, 64);
        HC += __shfl_down(HC, off, 64);
        SW += __shfl_down(SW, off, 64);
        SM += __shfl_down(SM, off, 64);
    }
    int w = u >> 6;
    if ((u & 63) == 0) { red[w][0] = HA; red[w][1] = HC; red[w][2] = SW; red[w][3] = SM; }
    __syncthreads();
    if (u == 0) {
        unsafeAtomicAdd(&accum[ACC_HANY],  red[0][0] + red[1][0]);
        unsafeAtomicAdd(&accum[ACC_HCONV], red[0][1] + red[1][1]);
        unsafeAtomicAdd(&accum[ACC_SW],    red[0][2] + red[1][2]);
        unsafeAtomicAdd(&accum[ACC_SM],    red[0][3] + red[1][3]);
    }
    for (int s = u; s < LBINS; s += 128)
        unsafeAtomicAdd(&accum[s], lb[s]);
}

// ---------------------------------------------------------------------------
__device__ double block_reduce_d(double v, double* buf) {
    int tid = threadIdx.x;
    buf[tid] = v;
    __syncthreads();
    for (int off = blockDim.x >> 1; off > 0; off >>= 1) {
        if (tid < off) buf[tid] += buf[tid + off];
        __syncthreads();
    }
    double r = buf[0];
    __syncthreads();
    return r;
}

__global__ __launch_bounds__(512)
void final_kernel(const unsigned char* __restrict__ flags,
                  const float* __restrict__ accum,
                  float* __restrict__ out, int B) {
    __shared__ double dred[512];
    int tid = threadIdx.x;
    int lane = tid & 63, w = tid >> 6;   // 8 waves

    // per-batch closed-form counts: wave w handles batches w, w+8, ...
    double ncW = 0.0, sameW = 0.0;
    for (int b = w; b < B; b += 8) {
        const unsigned char* bf = flags + (size_t)b * LBINS;
        int n1 = 0, nf = 0, nr = 0, na = 0, adj = 0;
        #pragma unroll
        for (int k = 0; k < 7; ++k) {
            int p = lane + 64 * k;
            if (p < LBINS) {
                int f = bf[p];
                n1 += (f >> 3) & 1; nf += f & 1; nr += (f >> 1) & 1; na += (f >> 2) & 1;
                if (p >= 1) {
                    int f2 = bf[p - 1];
                    adj += 1 - (((f ^ f2) >> 3) & 1);
                }
            }
        }
        #pragma unroll
        for (int off = 32; off > 0; off >>= 1) {
            n1 += __shfl_down(n1, off, 64);
            nf += __shfl_down(nf, off, 64);
            nr += __shfl_down(nr, off, 64);
            na += __shfl_down(na, off, 64);
            adj += __shfl_down(adj, off, 64);
        }
        if (lane == 0) {
            int n0 = LBINS - n1;
            ncW   += (double)na * na - (double)nf * nr;
            sameW += (double)n0 * n0 + (double)n1 * n1 - (double)LBINS - 2.0 * adj;
        }
    }
    double nc_sum   = block_reduce_d(ncW, dred);
    double same_cnt = block_reduce_d(sameW, dred);
    double total_maskf = (double)B * ((double)LL - 3.0 * LBINS + 2.0);
    double diff_cnt = total_maskf - same_cnt;

    // distance-decay regression over 401 bins
    float wgt = 0.f, x = 0.f, y = 0.f;
    if (tid < LBINS) {
        float cntB = ((tid == 0) ? (float)LBINS : 2.0f * (float)(LBINS - tid)) * (float)B;
        float mc = accum[tid] / cntB;
        int valid = (tid >= MIN_SEP) && __builtin_isfinite(mc) && (mc > 0.0f);
        wgt = valid ? 1.f : 0.f;
        x = logf(fmaxf((float)tid, 1.0f));
        y = logf((valid ? mc : 1.0f) + 1e-6f);
    }
    double n  = block_reduce_d((double)wgt, dred);
    double Sx = block_reduce_d((double)wgt * x, dred);
    double Sy = block_reduce_d((double)wgt * y, dred);
    double n_safe = fmax(n, 1.0);
    double xm = Sx / n_safe, ym = Sy / n_safe;
    double num = block_reduce_d((double)wgt * ((double)x - xm) * ((double)y - ym), dred);
    double den = block_reduce_d((double)wgt * ((double)x - xm) * ((double)x - xm), dred);

    if (tid == 0) {
        double slope = num / (den + 1e-8);
        float dist_loss = (n >= 5.0) ? (float)((slope + 0.85) * (slope + 0.85)) : 0.0f;

        float ncf = (float)nc_sum;
        float hinge = (accum[ACC_HANY] - accum[ACC_HCONV]) / (ncf + 1e-6f);
        float ctcf_loss = (ncf < 1.0f) ? 0.0f : hinge;

        float within_num  = accum[ACC_SW];
        float between_num = accum[ACC_SM] - within_num;
        float within  = within_num  / (float)fmax(same_cnt, 1.0);
        float between = between_num / (float)fmax(diff_cnt, 1.0);
        float ratio = within / (fabsf(between) + 1e-6f);
        float comp_loss = fmaxf(1.5f - ratio, 0.0f);

        float total = 1.0f * dist_loss + 0.5f * ctcf_loss + 0.5f * comp_loss;
        out[0] = dist_loss;
        out[1] = ctcf_loss;
        out[2] = comp_loss;
        out[3] = total;
    }
}

// ---------------------------------------------------------------------------
extern "C" void kernel_launch(void* const* d_in, const int* in_sizes, int n_in,
                              void* d_out, int out_size, void* d_ws, size_t ws_size,
                              hipStream_t stream) {
    const float* cm     = (const float*)d_in[0];   // (B, L, L) fp32
    const float* logits = (const float*)d_in[1];   // (B, L, 2) fp32
    const int*   ctcf   = (const int*)d_in[2];     // (B, L) int32
    float* out = (float*)d_out;

    int total = in_sizes[0];
    int B = total / LL;
    int BL = B * LBINS;

    float* accum = (float*)d_ws;
    unsigned char* flags = (unsigned char*)d_ws + 512 * sizeof(float);

    zero_kernel<<<1, 512, 0, stream>>>(accum);
    prep_kernel<<<(BL + 255) / 256, 256, 0, stream>>>(logits, ctcf, flags, BL);
    main_kernel<<<dim3(B, ROWG), 128, 0, stream>>>(cm, logits, ctcf, accum, B);
    final_kernel<<<1, 512, 0, stream>>>(flags, accum, out, B);
}

// Round 5
// 500.562 us; speedup vs baseline: 1.1659x; 1.1659x over previous
//
#include <hip/hip_runtime.h>
#include <cmath>

#define LBINS 401
#define LL 160801
#define MIN_SEP 2
#define RPB 67
#define ROWG 6      // 6*67 = 402 >= 401

// accum float layout
#define ACC_HANY  401   // sum relu(c)*any_i*any_j       (all pairs)
#define ACC_HCONV 402   // sum relu(c)*fwd_i*rev_j       (all pairs)
#define ACC_SWF   403   // sum c*same                    (all pairs)
#define ACC_ND    404   // sum_{|i-j|=1} c*same
#define ZERO_FLOATS 412
#define DBL_OFF 408     // byte offset 1632, 8-aligned: [0]=nc_sum, [1]=same_cnt

// ---------------------------------------------------------------------------
__global__ void zero_kernel(float* __restrict__ wsf) {
    int t = threadIdx.x;
    if (t < ZERO_FLOATS) wsf[t] = 0.0f;
}

// ---------------------------------------------------------------------------
// prep: one block per batch. Per-batch closed-form counts (fp64 atomics) and
// the adjacent-pair same-compartment correction ND.
// ---------------------------------------------------------------------------
__global__ __launch_bounds__(128)
void prep_kernel(const float* __restrict__ cm,
                 const float* __restrict__ logits,
                 const int* __restrict__ ctcf,
                 float* __restrict__ accum,
                 double* __restrict__ accd) {
    int b = blockIdx.x;
    int tid = threadIdx.x;
    int n1 = 0, nf = 0, nr = 0, na = 0, adj = 0;
    float nd = 0.f;
    const float* lg = logits + (size_t)b * LBINS * 2;
    const int*   ct = ctcf   + (size_t)b * LBINS;
    const float* cb = cm     + (size_t)b * LL;
    for (int l = tid; l < LBINS; l += 128) {
        int o = ct[l];
        int ci = (lg[2 * l + 1] > lg[2 * l]) ? 1 : 0;
        n1 += ci;
        nf += (o == 1);
        nr += (o == -1);
        na += (o != 0);
        if (l >= 1) {
            int cp = (lg[2 * (l - 1) + 1] > lg[2 * (l - 1)]) ? 1 : 0;
            adj += (ci == cp);
        }
        if (l + 1 < LBINS) {
            int cn = (lg[2 * (l + 1) + 1] > lg[2 * (l + 1)]) ? 1 : 0;
            if (cn == ci) nd += cb[(size_t)l * LBINS + l + 1] + cb[(size_t)(l + 1) * LBINS + l];
        }
    }
    #pragma unroll
    for (int off = 32; off > 0; off >>= 1) {
        n1 += __shfl_down(n1, off, 64);
        nf += __shfl_down(nf, off, 64);
        nr += __shfl_down(nr, off, 64);
        na += __shfl_down(na, off, 64);
        adj += __shfl_down(adj, off, 64);
        nd += __shfl_down(nd, off, 64);
    }
    __shared__ int   ired[2][5];
    __shared__ float fred[2];
    int w = tid >> 6;
    if ((tid & 63) == 0) {
        ired[w][0] = n1; ired[w][1] = nf; ired[w][2] = nr; ired[w][3] = na; ired[w][4] = adj;
        fred[w] = nd;
    }
    __syncthreads();
    if (tid == 0) {
        int N1 = ired[0][0] + ired[1][0];
        int NF = ired[0][1] + ired[1][1];
        int NR = ired[0][2] + ired[1][2];
        int NA = ired[0][3] + ired[1][3];
        int AD = ired[0][4] + ired[1][4];
        int N0 = LBINS - N1;
        double nc_b   = (double)NA * NA - (double)NF * NR;
        double same_b = (double)N0 * N0 + (double)N1 * N1 - (double)LBINS - 2.0 * AD;
        unsafeAtomicAdd(&accd[0], nc_b);
        unsafeAtomicAdd(&accd[1], same_b);
        unsafeAtomicAdd(&accum[ACC_ND], fred[0] + fred[1]);
    }
}

// ---------------------------------------------------------------------------
// main: block = (batch b, 67-row slice). Thread u owns columns u and u+256.
// Column masks in registers, row masks in LDS. Explicit row-pair software
// pipeline with compiler scheduling fences to keep 4 loads in flight.
// Per element: load + 5 VALU + abs + 1 LDS atomic. No distance-mask math
// (recovered in final from bins).
// ---------------------------------------------------------------------------
__global__ __launch_bounds__(256)
void main_kernel(const float* __restrict__ cm,
                 const float* __restrict__ logits,
                 const int* __restrict__ ctcf,
                 float* __restrict__ accum,
                 int B) {
    int b  = blockIdx.x;
    int i0 = blockIdx.y * RPB;
    int nrows = LBINS - i0; if (nrows > RPB) nrows = RPB;
    int u = threadIdx.x;

    __shared__ float  lb[LBINS];
    __shared__ float4 rowf[RPB];
    __shared__ float  red[4][3];

    for (int s = u; s < LBINS; s += 256) lb[s] = 0.f;
    if (u < nrows) {
        int idx = b * LBINS + i0 + u;
        int o = ctcf[idx];
        rowf[u] = make_float4((o != 0) ? 1.f : 0.f,
                              (o == 1) ? 1.f : 0.f,
                              (logits[2 * idx + 1] > logits[2 * idx]) ? 1.f : 0.f,
                              0.f);
    }

    // column masks in registers
    int  j0 = u;
    bool ok1 = (u + 256) < LBINS;
    int  j1 = ok1 ? (u + 256) : 0;
    int idx0 = b * LBINS + j0;
    int idx1 = b * LBINS + j1;
    int o0 = ctcf[idx0], o1 = ctcf[idx1];
    float any0 = (o0 != 0) ? 1.f : 0.f;
    float rev0 = (o0 == -1) ? 1.f : 0.f;
    float cmp0 = (logits[2 * idx0 + 1] > logits[2 * idx0]) ? 1.f : 0.f;
    float any1 = (ok1 && o1 != 0) ? 1.f : 0.f;
    float rev1 = (ok1 && o1 == -1) ? 1.f : 0.f;
    float cmp1 = (ok1 && (logits[2 * idx1 + 1] > logits[2 * idx1])) ? 1.f : 0.f;
    __syncthreads();

    const float* base = cm + (size_t)b * LL + (size_t)i0 * LBINS;
    float HA = 0.f, HC = 0.f, SW = 0.f;

    int e0 = j0 - i0;   // d for row r is |r - e|
    int e1 = j1 - i0;

#define COMPUTE_ROW(RR, C0, C1)                                   \
    {                                                             \
        float4 rf = rowf[(RR)];                                   \
        float rc0 = fmaxf((C0), 0.f), rc1 = fmaxf((C1), 0.f);     \
        float an = rc0 * any0 + rc1 * any1;                       \
        float rv = rc0 * rev0 + rc1 * rev1;                       \
        float p1 = (C0) * cmp0 + (C1) * cmp1;                     \
        float smr = (C0) + (C1);                                  \
        HA = fmaf(rf.x, an, HA);                                  \
        HC = fmaf(rf.y, rv, HC);                                  \
        SW += (rf.z != 0.f) ? p1 : (smr - p1);                    \
        int d0 = (RR) - e0; d0 = d0 < 0 ? -d0 : d0;               \
        int d1 = (RR) - e1; d1 = d1 < 0 ? -d1 : d1;               \
        atomicAdd(&lb[d0], (C0));                                 \
        atomicAdd(&lb[d1], (C1));                                 \
    }

    int npairs = nrows >> 1;
    int r = 0;
    if (npairs > 0) {
        const float* p = base;
        float c00 = p[j0];
        float c01 = ok1 ? p[j1] : 0.f;
        float c10 = p[LBINS + j0];
        float c11 = ok1 ? p[LBINS + j1] : 0.f;
        for (int pr = 0; pr < npairs; ++pr) {
            const float* pn = (pr + 1 < npairs) ? (p + 2 * LBINS) : p;
            float n00 = pn[j0];
            float n01 = ok1 ? pn[j1] : 0.f;
            float n10 = pn[LBINS + j0];
            float n11 = ok1 ? pn[LBINS + j1] : 0.f;
            asm volatile("" ::: "memory");
            COMPUTE_ROW(r,     c00, c01);
            COMPUTE_ROW(r + 1, c10, c11);
            asm volatile("" ::: "memory");
            c00 = n00; c01 = n01; c10 = n10; c11 = n11;
            p += 2 * LBINS;
            r += 2;
        }
    }
    if (r < nrows) {   // odd tail row
        const float* p = base + (size_t)r * LBINS;
        float c0 = p[j0];
        float c1 = ok1 ? p[j1] : 0.f;
        COMPUTE_ROW(r, c0, c1);
    }
#undef COMPUTE_ROW

    #pragma unroll
    for (int off = 32; off > 0; off >>= 1) {
        HA += __shfl_down(HA, off, 64);
        HC += __shfl_down(HC, off, 64);
        SW += __shfl_down(SW, off, 64);
    }
    int w = u >> 6;
    if ((u & 63) == 0) { red[w][0] = HA; red[w][1] = HC; red[w][2] = SW; }
    __syncthreads();
    if (u == 0) {
        float a = 0.f, c = 0.f, s = 0.f;
        #pragma unroll
        for (int k = 0; k < 4; ++k) { a += red[k][0]; c += red[k][1]; s += red[k][2]; }
        unsafeAtomicAdd(&accum[ACC_HANY],  a);
        unsafeAtomicAdd(&accum[ACC_HCONV], c);
        unsafeAtomicAdd(&accum[ACC_SWF],   s);
    }
    for (int s2 = u; s2 < LBINS; s2 += 256)
        unsafeAtomicAdd(&accum[s2], lb[s2]);
}

// ---------------------------------------------------------------------------
__device__ double block_reduce_d(double v, double* buf) {
    int tid = threadIdx.x;
    buf[tid] = v;
    __syncthreads();
    for (int off = blockDim.x >> 1; off > 0; off >>= 1) {
        if (tid < off) buf[tid] += buf[tid + off];
        __syncthreads();
    }
    double r = buf[0];
    __syncthreads();
    return r;
}

__global__ __launch_bounds__(512)
void final_kernel(const float* __restrict__ accum,
                  const double* __restrict__ accd,
                  float* __restrict__ out, int B) {
    __shared__ double dred[512];
    int tid = threadIdx.x;

    double nc_sum   = accd[0];
    double same_cnt = accd[1];
    double total_maskf = (double)B * ((double)LL - 3.0 * LBINS + 2.0);
    double diff_cnt = total_maskf - same_cnt;

    // bins total + regression
    float bv = (tid < LBINS) ? accum[tid] : 0.f;
    double binsum = block_reduce_d((double)bv, dred);

    float wgt = 0.f, x = 0.f, y = 0.f;
    if (tid < LBINS) {
        float cntB = ((tid == 0) ? (float)LBINS : 2.0f * (float)(LBINS - tid)) * (float)B;
        float mc = bv / cntB;
        int valid = (tid >= MIN_SEP) && __builtin_isfinite(mc) && (mc > 0.0f);
        wgt = valid ? 1.f : 0.f;
        x = logf(fmaxf((float)tid, 1.0f));
        y = logf((valid ? mc : 1.0f) + 1e-6f);
    }
    double n  = block_reduce_d((double)wgt, dred);
    double Sx = block_reduce_d((double)wgt * x, dred);
    double Sy = block_reduce_d((double)wgt * y, dred);
    double n_safe = fmax(n, 1.0);
    double xm = Sx / n_safe, ym = Sy / n_safe;
    double num = block_reduce_d((double)wgt * ((double)x - xm) * ((double)y - ym), dred);
    double den = block_reduce_d((double)wgt * ((double)x - xm) * ((double)x - xm), dred);

    if (tid == 0) {
        double slope = num / (den + 1e-8);
        float dist_loss = (n >= 5.0) ? (float)((slope + 0.85) * (slope + 0.85)) : 0.0f;

        float ncf = (float)nc_sum;
        float hinge = (accum[ACC_HANY] - accum[ACC_HCONV]) / (ncf + 1e-6f);
        float ctcf_loss = (ncf < 1.0f) ? 0.0f : hinge;

        float bin0 = accum[0], bin1 = accum[1];
        float SW_m = accum[ACC_SWF] - bin0 - accum[ACC_ND];
        float SM_m = (float)binsum - bin0 - bin1;
        float within  = SW_m / (float)fmax(same_cnt, 1.0);
        float between = (SM_m - SW_m) / (float)fmax(diff_cnt, 1.0);
        float ratio = within / (fabsf(between) + 1e-6f);
        float comp_loss = fmaxf(1.5f - ratio, 0.0f);

        float total = 1.0f * dist_loss + 0.5f * ctcf_loss + 0.5f * comp_loss;
        out[0] = dist_loss;
        out[1] = ctcf_loss;
        out[2] = comp_loss;
        out[3] = total;
    }
}

// ---------------------------------------------------------------------------
extern "C" void kernel_launch(void* const* d_in, const int* in_sizes, int n_in,
                              void* d_out, int out_size, void* d_ws, size_t ws_size,
                              hipStream_t stream) {
    const float* cm     = (const float*)d_in[0];   // (B, L, L) fp32
    const float* logits = (const float*)d_in[1];   // (B, L, 2) fp32
    const int*   ctcf   = (const int*)d_in[2];     // (B, L) int32
    float* out = (float*)d_out;

    int total = in_sizes[0];
    int B = total / LL;

    float*  accum = (float*)d_ws;
    double* accd  = (double*)((float*)d_ws + DBL_OFF);

    zero_kernel<<<1, 512, 0, stream>>>(accum);
    prep_kernel<<<B, 128, 0, stream>>>(cm, logits, ctcf, accum, accd);
    main_kernel<<<dim3(B, ROWG), 256, 0, stream>>>(cm, logits, ctcf, accum, B);
    final_kernel<<<1, 512, 0, stream>>>(accum, accd, out, B);
}

// Round 6
// 263.112 us; speedup vs baseline: 2.2182x; 1.9025x over previous
//
#include <hip/hip_runtime.h>
#include <cmath>

#define LBINS 401
#define LL 160801
#define MIN_SEP 2
#define NBY 8            // 4 diagonal bands x 2 i-halves
#define PSTRIDE 405      // per-partial floats: 401 bins + HA,HC,SWm,SMm

// accum layout (floats)
#define ACC_HANY  401
#define ACC_HCONV 402
#define ACC_SWM   403
#define ACC_SMM   404
#define ACCD_OFF  416    // float idx; byte 1664 (8-aligned): accd[0]=nc, [1]=same
#define ZERO_FLOATS 420
#define PARTS_OFF 512    // float idx

// ---------------------------------------------------------------------------
__global__ void zero_kernel(float* __restrict__ wsf) {
    int t = threadIdx.x;
    if (t < ZERO_FLOATS) wsf[t] = 0.0f;
}

// ---------------------------------------------------------------------------
// prep: per-batch closed-form counts only (no cm reads).
// ---------------------------------------------------------------------------
__global__ __launch_bounds__(128)
void prep_kernel(const float* __restrict__ logits,
                 const int* __restrict__ ctcf,
                 double* __restrict__ accd) {
    int b = blockIdx.x;
    int tid = threadIdx.x;
    int n1 = 0, nf = 0, nr = 0, na = 0, adj = 0;
    const float* lg = logits + (size_t)b * LBINS * 2;
    const int*   ct = ctcf   + (size_t)b * LBINS;
    for (int l = tid; l < LBINS; l += 128) {
        int o = ct[l];
        int ci = (lg[2 * l + 1] > lg[2 * l]) ? 1 : 0;
        n1 += ci; nf += (o == 1); nr += (o == -1); na += (o != 0);
        if (l >= 1) {
            int cp = (lg[2 * (l - 1) + 1] > lg[2 * (l - 1)]) ? 1 : 0;
            adj += (ci == cp);
        }
    }
    #pragma unroll
    for (int off = 32; off > 0; off >>= 1) {
        n1 += __shfl_down(n1, off, 64);
        nf += __shfl_down(nf, off, 64);
        nr += __shfl_down(nr, off, 64);
        na += __shfl_down(na, off, 64);
        adj += __shfl_down(adj, off, 64);
    }
    __shared__ int ired[2][5];
    int w = tid >> 6;
    if ((tid & 63) == 0) {
        ired[w][0] = n1; ired[w][1] = nf; ired[w][2] = nr;
        ired[w][3] = na; ired[w][4] = adj;
    }
    __syncthreads();
    if (tid == 0) {
        int N1 = ired[0][0] + ired[1][0];
        int NF = ired[0][1] + ired[1][1];
        int NR = ired[0][2] + ired[1][2];
        int NA = ired[0][3] + ired[1][3];
        int AD = ired[0][4] + ired[1][4];
        int N0 = LBINS - N1;
        unsafeAtomicAdd(&accd[0], (double)NA * NA - (double)NF * NR);
        unsafeAtomicAdd(&accd[1],
            (double)N0 * N0 + (double)N1 * N1 - (double)LBINS - 2.0 * AD);
    }
}

// ---------------------------------------------------------------------------
// diag: block = (batch b, band/half). Lane owns diagonal k = -400+256*band+u;
// d=|k| constant per lane -> bins/maskf are register accumulators. Inner
// loop: 1 coalesced global load + 2 LDS reads + FMA. No atomics in loop.
// ---------------------------------------------------------------------------
__global__ __launch_bounds__(256)
void diag_kernel(const float* __restrict__ cm,
                 const float* __restrict__ logits,
                 const int* __restrict__ ctcf,
                 float* __restrict__ parts) {
    int b    = blockIdx.x;
    int band = blockIdx.y >> 1;
    int half = blockIdx.y & 1;
    int u    = threadIdx.x;
    int ka   = -400 + 256 * band;
    int k    = ka + u;

    __shared__ float4 colm[LBINS];   // (any_j, rev_j, c_j, 0)
    __shared__ float4 rowm[LBINS];   // (any_i, fwd_i, 2c_i-1, 1-c_i)
    __shared__ float  lb[LBINS];
    __shared__ float  sred[4][4];

    const int*   ct = ctcf   + (size_t)b * LBINS;
    const float* lg = logits + (size_t)b * LBINS * 2;
    for (int t = u; t < LBINS; t += 256) {
        int o = ct[t];
        float any = (o != 0) ? 1.f : 0.f;
        float rev = (o == -1) ? 1.f : 0.f;
        float fwd = (o == 1) ? 1.f : 0.f;
        float cj  = (lg[2 * t + 1] > lg[2 * t]) ? 1.f : 0.f;
        colm[t] = make_float4(any, rev, cj, 0.f);
        rowm[t] = make_float4(any, fwd, 2.f * cj - 1.f, 1.f - cj);
        lb[t] = 0.f;
    }
    __syncthreads();

    int i_lo = max(0, -(ka + 255));
    int i_hi = min(LBINS, LBINS - ka);
    int len  = i_hi - i_lo;
    int mid  = i_lo + ((len + 1) >> 1);
    int is   = half ? mid : i_lo;
    int ie   = half ? i_hi : mid;

    const float* cmb = cm + (size_t)b * LL;
    float HA = 0.f, HC = 0.f, SW = 0.f, SM = 0.f;

    int i = is;
    for (; i + 4 <= ie; i += 4) {
        float  c[4];
        float4 cj4[4], rm4[4];
        #pragma unroll
        for (int q = 0; q < 4; ++q) {
            int ii = i + q;
            int j  = ii + k;
            int jc = min(max(j, 0), LBINS - 1);
            rm4[q] = rowm[ii];
            cj4[q] = colm[jc];
            float craw = cmb[(size_t)ii * LBINS + jc];
            c[q] = ((unsigned)j < (unsigned)LBINS) ? craw : 0.f;
        }
        #pragma unroll
        for (int q = 0; q < 4; ++q) {
            float cv = c[q];
            float rc = fmaxf(cv, 0.f);
            HA = fmaf(rm4[q].x * cj4[q].x, rc, HA);
            HC = fmaf(rm4[q].y * cj4[q].y, rc, HC);
            float sel = fmaf(rm4[q].z, cj4[q].z, rm4[q].w);  // same-compartment
            SW = fmaf(sel, cv, SW);
            SM += cv;
        }
    }
    for (; i < ie; ++i) {
        int j  = i + k;
        int jc = min(max(j, 0), LBINS - 1);
        float4 rm = rowm[i];
        float4 cj = colm[jc];
        float craw = cmb[(size_t)i * LBINS + jc];
        float cv = ((unsigned)j < (unsigned)LBINS) ? craw : 0.f;
        float rc = fmaxf(cv, 0.f);
        HA = fmaf(rm.x * cj.x, rc, HA);
        HC = fmaf(rm.y * cj.y, rc, HC);
        float sel = fmaf(rm.z, cj.z, rm.w);
        SW = fmaf(sel, cv, SW);
        SM += cv;
    }

    // per-lane epilogue: d = |k| constant
    int d = k < 0 ? -k : k; if (d > LBINS - 1) d = LBINS - 1;
    float dmask = (d >= MIN_SEP) ? 1.f : 0.f;
    atomicAdd(&lb[d], SM);
    float SWm = SW * dmask;
    float SMm = SM * dmask;

    #pragma unroll
    for (int off = 32; off > 0; off >>= 1) {
        HA  += __shfl_down(HA,  off, 64);
        HC  += __shfl_down(HC,  off, 64);
        SWm += __shfl_down(SWm, off, 64);
        SMm += __shfl_down(SMm, off, 64);
    }
    int w = u >> 6;
    if ((u & 63) == 0) {
        sred[w][0] = HA; sred[w][1] = HC; sred[w][2] = SWm; sred[w][3] = SMm;
    }
    __syncthreads();

    float* pout = parts + (size_t)(blockIdx.y * gridDim.x + blockIdx.x) * PSTRIDE;
    for (int t = u; t < LBINS; t += 256) pout[t] = lb[t];
    if (u == 0) {
        float a = 0.f, c2 = 0.f, s = 0.f, m = 0.f;
        #pragma unroll
        for (int q = 0; q < 4; ++q) {
            a += sred[q][0]; c2 += sred[q][1]; s += sred[q][2]; m += sred[q][3];
        }
        pout[401] = a; pout[402] = c2; pout[403] = s; pout[404] = m;
    }
}

// ---------------------------------------------------------------------------
// reduce: block s sums column s over all partials -> accum[s].
// ---------------------------------------------------------------------------
__global__ __launch_bounds__(256)
void reduce_kernel(const float* __restrict__ parts,
                   float* __restrict__ accum, int npart) {
    int s = blockIdx.x;
    int u = threadIdx.x;
    float acc = 0.f;
    for (int p = u; p < npart; p += 256) acc += parts[(size_t)p * PSTRIDE + s];
    #pragma unroll
    for (int off = 32; off > 0; off >>= 1) acc += __shfl_down(acc, off, 64);
    __shared__ float r[4];
    if ((u & 63) == 0) r[u >> 6] = acc;
    __syncthreads();
    if (u == 0) accum[s] = r[0] + r[1] + r[2] + r[3];
}

// ---------------------------------------------------------------------------
__device__ double block_reduce_d(double v, double* buf) {
    int tid = threadIdx.x;
    buf[tid] = v;
    __syncthreads();
    for (int off = blockDim.x >> 1; off > 0; off >>= 1) {
        if (tid < off) buf[tid] += buf[tid + off];
        __syncthreads();
    }
    double r = buf[0];
    __syncthreads();
    return r;
}

__global__ __launch_bounds__(512)
void final_kernel(const float* __restrict__ accum,
                  const double* __restrict__ accd,
                  float* __restrict__ out, int B) {
    __shared__ double dred[512];
    int tid = threadIdx.x;

    double nc_sum   = accd[0];
    double same_cnt = accd[1];
    double total_maskf = (double)B * ((double)LL - 3.0 * LBINS + 2.0);
    double diff_cnt = total_maskf - same_cnt;

    float wgt = 0.f, x = 0.f, y = 0.f;
    if (tid < LBINS) {
        float cntB = ((tid == 0) ? (float)LBINS : 2.0f * (float)(LBINS - tid)) * (float)B;
        float mc = accum[tid] / cntB;
        int valid = (tid >= MIN_SEP) && __builtin_isfinite(mc) && (mc > 0.0f);
        wgt = valid ? 1.f : 0.f;
        x = logf(fmaxf((float)tid, 1.0f));
        y = logf((valid ? mc : 1.0f) + 1e-6f);
    }
    double n  = block_reduce_d((double)wgt, dred);
    double Sx = block_reduce_d((double)wgt * x, dred);
    double Sy = block_reduce_d((double)wgt * y, dred);
    double n_safe = fmax(n, 1.0);
    double xm = Sx / n_safe, ym = Sy / n_safe;
    double num = block_reduce_d((double)wgt * ((double)x - xm) * ((double)y - ym), dred);
    double den = block_reduce_d((double)wgt * ((double)x - xm) * ((double)x - xm), dred);

    if (tid == 0) {
        double slope = num / (den + 1e-8);
        float dist_loss = (n >= 5.0) ? (float)((slope + 0.85) * (slope + 0.85)) : 0.0f;

        float ncf = (float)nc_sum;
        float hinge = (accum[ACC_HANY] - accum[ACC_HCONV]) / (ncf + 1e-6f);
        float ctcf_loss = (ncf < 1.0f) ? 0.0f : hinge;

        float SW_m = accum[ACC_SWM];
        float SM_m = accum[ACC_SMM];
        float within  = SW_m / (float)fmax(same_cnt, 1.0);
        float between = (SM_m - SW_m) / (float)fmax(diff_cnt, 1.0);
        float ratio = within / (fabsf(between) + 1e-6f);
        float comp_loss = fmaxf(1.5f - ratio, 0.0f);

        float total = 1.0f * dist_loss + 0.5f * ctcf_loss + 0.5f * comp_loss;
        out[0] = dist_loss;
        out[1] = ctcf_loss;
        out[2] = comp_loss;
        out[3] = total;
    }
}

// ---------------------------------------------------------------------------
extern "C" void kernel_launch(void* const* d_in, const int* in_sizes, int n_in,
                              void* d_out, int out_size, void* d_ws, size_t ws_size,
                              hipStream_t stream) {
    const float* cm     = (const float*)d_in[0];   // (B, L, L) fp32
    const float* logits = (const float*)d_in[1];   // (B, L, 2) fp32
    const int*   ctcf   = (const int*)d_in[2];     // (B, L) int32
    float* out = (float*)d_out;

    int total = in_sizes[0];
    int B = total / LL;

    float*  wsf   = (float*)d_ws;
    float*  accum = wsf;
    double* accd  = (double*)(wsf + ACCD_OFF);
    float*  parts = wsf + PARTS_OFF;
    int npart = NBY * B;

    zero_kernel<<<1, 512, 0, stream>>>(wsf);
    prep_kernel<<<B, 128, 0, stream>>>(logits, ctcf, accd);
    diag_kernel<<<dim3(B, NBY), 256, 0, stream>>>(cm, logits, ctcf, parts);
    reduce_kernel<<<PSTRIDE, 256, 0, stream>>>(parts, accum, npart);
    final_kernel<<<1, 512, 0, stream>>>(accum, accd, out, B);
}

// Round 7
// 256.336 us; speedup vs baseline: 2.2768x; 1.0264x over previous
//
#include <hip/hip_runtime.h>
#include <cmath>

#define LBINS 401
#define LL 160801
#define MIN_SEP 2
#define PSTRIDE 405      // per-partial floats: 401 bins + HA,HC,SWm,SMm
#define UNR 8

// accum layout (floats)
#define ACC_HANY  401
#define ACC_HCONV 402
#define ACC_SWM   403
#define ACC_SMM   404
#define ACCD_OFF  416    // float idx; byte 1664 (8-aligned): accd[0]=nc, [1]=same
#define PARTS_OFF 512    // float idx

// ---------------------------------------------------------------------------
__global__ void zero_kernel(double* __restrict__ accd) {
    if (threadIdx.x < 2) accd[threadIdx.x] = 0.0;
}

// ---------------------------------------------------------------------------
// prep: per-batch closed-form counts only (no cm reads).
// ---------------------------------------------------------------------------
__global__ __launch_bounds__(128)
void prep_kernel(const float* __restrict__ logits,
                 const int* __restrict__ ctcf,
                 double* __restrict__ accd) {
    int b = blockIdx.x;
    int tid = threadIdx.x;
    int n1 = 0, nf = 0, nr = 0, na = 0, adj = 0;
    const float* lg = logits + (size_t)b * LBINS * 2;
    const int*   ct = ctcf   + (size_t)b * LBINS;
    for (int l = tid; l < LBINS; l += 128) {
        int o = ct[l];
        int ci = (lg[2 * l + 1] > lg[2 * l]) ? 1 : 0;
        n1 += ci; nf += (o == 1); nr += (o == -1); na += (o != 0);
        if (l >= 1) {
            int cp = (lg[2 * (l - 1) + 1] > lg[2 * (l - 1)]) ? 1 : 0;
            adj += (ci == cp);
        }
    }
    #pragma unroll
    for (int off = 32; off > 0; off >>= 1) {
        n1 += __shfl_down(n1, off, 64);
        nf += __shfl_down(nf, off, 64);
        nr += __shfl_down(nr, off, 64);
        na += __shfl_down(na, off, 64);
        adj += __shfl_down(adj, off, 64);
    }
    __shared__ int ired[2][5];
    int w = tid >> 6;
    if ((tid & 63) == 0) {
        ired[w][0] = n1; ired[w][1] = nf; ired[w][2] = nr;
        ired[w][3] = na; ired[w][4] = adj;
    }
    __syncthreads();
    if (tid == 0) {
        int N1 = ired[0][0] + ired[1][0];
        int NF = ired[0][1] + ired[1][1];
        int NR = ired[0][2] + ired[1][2];
        int NA = ired[0][3] + ired[1][3];
        int AD = ired[0][4] + ired[1][4];
        int N0 = LBINS - N1;
        unsafeAtomicAdd(&accd[0], (double)NA * NA - (double)NF * NR);
        unsafeAtomicAdd(&accd[1],
            (double)N0 * N0 + (double)N1 * N1 - (double)LBINS - 2.0 * AD);
    }
}

// ---------------------------------------------------------------------------
// diag (skewed torus): lane owns diagonal k = 256*kgroup + u (k<401); walks
// i over its half-range with j = (i+k) mod 401 — bijective onto the matrix,
// 100% lane efficiency. d = k (no wrap) or 401-k (wrap): register
// accumulators, no atomics/barriers in the loop -> loads stay hoisted.
// ---------------------------------------------------------------------------
__global__ __launch_bounds__(256)
void diag_kernel(const float* __restrict__ cm,
                 const float* __restrict__ logits,
                 const int* __restrict__ ctcf,
                 float* __restrict__ parts) {
    int b      = blockIdx.x;
    int ihalf  = blockIdx.y & 1;
    int kgroup = blockIdx.y >> 1;
    int u      = threadIdx.x;
    int k      = kgroup * 256 + u;
    bool active = (k < LBINS);

    __shared__ float4 colm[LBINS];   // (any_j, rev_j, c_j, 0)
    __shared__ float4 rowm[LBINS];   // (any_i, fwd_i, 2c_i-1, 1-c_i)
    __shared__ float  lb[LBINS];
    __shared__ float  sred[4][4];

    const int*   ct = ctcf   + (size_t)b * LBINS;
    const float* lg = logits + (size_t)b * LBINS * 2;
    for (int t = u; t < LBINS; t += 256) {
        int o = ct[t];
        float any = (o != 0) ? 1.f : 0.f;
        float rev = (o == -1) ? 1.f : 0.f;
        float fwd = (o == 1) ? 1.f : 0.f;
        float cj  = (lg[2 * t + 1] > lg[2 * t]) ? 1.f : 0.f;
        colm[t] = make_float4(any, rev, cj, 0.f);
        rowm[t] = make_float4(any, fwd, 2.f * cj - 1.f, 1.f - cj);
        lb[t] = 0.f;
    }
    __syncthreads();

    int i0 = ihalf ? 201 : 0;
    int ie = ihalf ? LBINS : 201;

    const float* cmb = cm + (size_t)b * LL;
    float HA = 0.f, HC = 0.f;
    float SMk = 0.f, SMw = 0.f, SWk = 0.f, SWw = 0.f;

    if (active) {
        int i = i0;
        for (; i + UNR <= ie; i += UNR) {
            float  cv[UNR], sw[UNR];
            float4 cj4[UNR], rm4[UNR];
            #pragma unroll
            for (int q = 0; q < UNR; ++q) {
                int ii = i + q;
                int j  = ii + k;
                int wrapped = (j >= LBINS);
                int jc = wrapped ? j - LBINS : j;
                cv[q]  = cmb[(size_t)ii * LBINS + jc];
                cj4[q] = colm[jc];
                rm4[q] = rowm[ii];
                sw[q]  = wrapped ? 1.f : 0.f;
            }
            #pragma unroll
            for (int q = 0; q < UNR; ++q) {
                float c  = cv[q];
                float rc = fmaxf(c, 0.f);
                HA = fmaf(rm4[q].x * cj4[q].x, rc, HA);
                HC = fmaf(rm4[q].y * cj4[q].y, rc, HC);
                float same = fmaf(rm4[q].z, cj4[q].z, rm4[q].w);
                float sc = same * c;
                float s = sw[q];
                SWw = fmaf(s, sc, SWw);
                SWk = fmaf(1.f - s, sc, SWk);
                SMw = fmaf(s, c, SMw);
                SMk = fmaf(1.f - s, c, SMk);
            }
        }
        for (; i < ie; ++i) {
            int j  = i + k;
            int wrapped = (j >= LBINS);
            int jc = wrapped ? j - LBINS : j;
            float c = cmb[(size_t)i * LBINS + jc];
            float4 cjv = colm[jc];
            float4 rm  = rowm[i];
            float s = wrapped ? 1.f : 0.f;
            float rc = fmaxf(c, 0.f);
            HA = fmaf(rm.x * cjv.x, rc, HA);
            HC = fmaf(rm.y * cjv.y, rc, HC);
            float same = fmaf(rm.z, cjv.z, rm.w);
            float sc = same * c;
            SWw = fmaf(s, sc, SWw);
            SWk = fmaf(1.f - s, sc, SWk);
            SMw = fmaf(s, c, SMw);
            SMk = fmaf(1.f - s, c, SMk);
        }
    }

    // per-lane epilogue: bins via register sums (two per lane)
    float SWm = 0.f, SMm = 0.f;
    if (active) {
        int dw = LBINS - k;               // d of wrapped part (k>0)
        atomicAdd(&lb[k], SMk);
        if (k > 0) atomicAdd(&lb[dw], SMw);
        float mk = (k >= MIN_SEP) ? 1.f : 0.f;
        float mw = (dw >= MIN_SEP) ? 1.f : 0.f;
        SWm = SWk * mk + SWw * mw;
        SMm = SMk * mk + SMw * mw;
    }

    #pragma unroll
    for (int off = 32; off > 0; off >>= 1) {
        HA  += __shfl_down(HA,  off, 64);
        HC  += __shfl_down(HC,  off, 64);
        SWm += __shfl_down(SWm, off, 64);
        SMm += __shfl_down(SMm, off, 64);
    }
    int w = u >> 6;
    if ((u & 63) == 0) {
        sred[w][0] = HA; sred[w][1] = HC; sred[w][2] = SWm; sred[w][3] = SMm;
    }
    __syncthreads();

    float* pout = parts + (size_t)(blockIdx.y * gridDim.x + blockIdx.x) * PSTRIDE;
    for (int t = u; t < LBINS; t += 256) pout[t] = lb[t];
    if (u == 0) {
        float a = 0.f, c2 = 0.f, s = 0.f, m = 0.f;
        #pragma unroll
        for (int q = 0; q < 4; ++q) {
            a += sred[q][0]; c2 += sred[q][1]; s += sred[q][2]; m += sred[q][3];
        }
        pout[401] = a; pout[402] = c2; pout[403] = s; pout[404] = m;
    }
}

// ---------------------------------------------------------------------------
// reduce: block s sums column s over all partials -> accum[s] (plain store).
// ---------------------------------------------------------------------------
__global__ __launch_bounds__(256)
void reduce_kernel(const float* __restrict__ parts,
                   float* __restrict__ accum, int npart) {
    int s = blockIdx.x;
    int u = threadIdx.x;
    float acc = 0.f;
    for (int p = u; p < npart; p += 256) acc += parts[(size_t)p * PSTRIDE + s];
    #pragma unroll
    for (int off = 32; off > 0; off >>= 1) acc += __shfl_down(acc, off, 64);
    __shared__ float r[4];
    if ((u & 63) == 0) r[u >> 6] = acc;
    __syncthreads();
    if (u == 0) accum[s] = r[0] + r[1] + r[2] + r[3];
}

// ---------------------------------------------------------------------------
__device__ double block_reduce_d(double v, double* buf) {
    int tid = threadIdx.x;
    buf[tid] = v;
    __syncthreads();
    for (int off = blockDim.x >> 1; off > 0; off >>= 1) {
        if (tid < off) buf[tid] += buf[tid + off];
        __syncthreads();
    }
    double r = buf[0];
    __syncthreads();
    return r;
}

__global__ __launch_bounds__(512)
void final_kernel(const float* __restrict__ accum,
                  const double* __restrict__ accd,
                  float* __restrict__ out, int B) {
    __shared__ double dred[512];
    int tid = threadIdx.x;

    double nc_sum   = accd[0];
    double same_cnt = accd[1];
    double total_maskf = (double)B * ((double)LL - 3.0 * LBINS + 2.0);
    double diff_cnt = total_maskf - same_cnt;

    float wgt = 0.f, x = 0.f, y = 0.f;
    if (tid < LBINS) {
        float cntB = ((tid == 0) ? (float)LBINS : 2.0f * (float)(LBINS - tid)) * (float)B;
        float mc = accum[tid] / cntB;
        int valid = (tid >= MIN_SEP) && __builtin_isfinite(mc) && (mc > 0.0f);
        wgt = valid ? 1.f : 0.f;
        x = logf(fmaxf((float)tid, 1.0f));
        y = logf((valid ? mc : 1.0f) + 1e-6f);
    }
    double n  = block_reduce_d((double)wgt, dred);
    double Sx = block_reduce_d((double)wgt * x, dred);
    double Sy = block_reduce_d((double)wgt * y, dred);
    double n_safe = fmax(n, 1.0);
    double xm = Sx / n_safe, ym = Sy / n_safe;
    double num = block_reduce_d((double)wgt * ((double)x - xm) * ((double)y - ym), dred);
    double den = block_reduce_d((double)wgt * ((double)x - xm) * ((double)x - xm), dred);

    if (tid == 0) {
        double slope = num / (den + 1e-8);
        float dist_loss = (n >= 5.0) ? (float)((slope + 0.85) * (slope + 0.85)) : 0.0f;

        float ncf = (float)nc_sum;
        float hinge = (accum[ACC_HANY] - accum[ACC_HCONV]) / (ncf + 1e-6f);
        float ctcf_loss = (ncf < 1.0f) ? 0.0f : hinge;

        float SW_m = accum[ACC_SWM];
        float SM_m = accum[ACC_SMM];
        float within  = SW_m / (float)fmax(same_cnt, 1.0);
        float between = (SM_m - SW_m) / (float)fmax(diff_cnt, 1.0);
        float ratio = within / (fabsf(between) + 1e-6f);
        float comp_loss = fmaxf(1.5f - ratio, 0.0f);

        float total = 1.0f * dist_loss + 0.5f * ctcf_loss + 0.5f * comp_loss;
        out[0] = dist_loss;
        out[1] = ctcf_loss;
        out[2] = comp_loss;
        out[3] = total;
    }
}

// ---------------------------------------------------------------------------
extern "C" void kernel_launch(void* const* d_in, const int* in_sizes, int n_in,
                              void* d_out, int out_size, void* d_ws, size_t ws_size,
                              hipStream_t stream) {
    const float* cm     = (const float*)d_in[0];   // (B, L, L) fp32
    const float* logits = (const float*)d_in[1];   // (B, L, 2) fp32
    const int*   ctcf   = (const int*)d_in[2];     // (B, L) int32
    float* out = (float*)d_out;

    int total = in_sizes[0];
    int B = total / LL;

    float*  wsf   = (float*)d_ws;
    float*  accum = wsf;
    double* accd  = (double*)(wsf + ACCD_OFF);
    float*  parts = wsf + PARTS_OFF;
    int npart = 4 * B;

    zero_kernel<<<1, 64, 0, stream>>>(accd);
    prep_kernel<<<B, 128, 0, stream>>>(logits, ctcf, accd);
    diag_kernel<<<dim3(B, 4), 256, 0, stream>>>(cm, logits, ctcf, parts);
    reduce_kernel<<<PSTRIDE, 256, 0, stream>>>(parts, accum, npart);
    final_kernel<<<1, 512, 0, stream>>>(accum, accd, out, B);
}